// Round 4
// baseline (491.711 us; speedup 1.0000x reference)
//
#include <hip/hip_runtime.h>

// InternalInteraction: out[b,j,d] = sum_i [ relu((x_i*x_j)@W1^T + b1) @ W2^T + b2 ]
// Factored: hsum[b,j,h] = sum_i relu((x_i*x_j)@W1^T + b1); out = hsum@W2^T + 16*b2.
// B=2048, A=16, D=128, H=512. Storage fp32 (bf16-rounded values); MFMA in bf16.
//
// Round-4 structure (fixes round-3's W1-reload L2 bottleneck):
//  - 512-thread blocks (8 waves); wave owns 64 h -> w1f is only 64 VGPRs and
//    is loaded ONCE (fp32->bf16 inline), genuinely register-resident under
//    the __launch_bounds__(512,4) 128-VGPR cap (2 blocks/CU).
//  - pair tile double-buffered in LDS, ONE barrier per i; the build of tile
//    i+1 is issued between the af reads and the MFMA chain so its LDS/VALU
//    cost hides under 16 MFMAs.
//  - single kernel launch (no prologue, no workspace).

#define BATCH 2048
#define AA 16
#define DD 128
#define HH 512

typedef __bf16 bf16;
typedef bf16  bf16x4 __attribute__((ext_vector_type(4)));
typedef bf16  bf16x8 __attribute__((ext_vector_type(8)));
typedef float f32x4  __attribute__((ext_vector_type(4)));

__device__ inline f32x4 splat4(float v) { f32x4 r = {v, v, v, v}; return r; }

__device__ inline bf16x4 cvt4(const f32x4& v) {
    bf16x4 r;
    r[0] = (bf16)v[0]; r[1] = (bf16)v[1]; r[2] = (bf16)v[2]; r[3] = (bf16)v[3];
    return r;
}
__device__ inline bf16x8 cvt8(const f32x4& lo, const f32x4& hi) {
    bf16x8 r;
    r[0] = (bf16)lo[0]; r[1] = (bf16)lo[1]; r[2] = (bf16)lo[2]; r[3] = (bf16)lo[3];
    r[4] = (bf16)hi[0]; r[5] = (bf16)hi[1]; r[6] = (bf16)hi[2]; r[7] = (bf16)hi[3];
    return r;
}

// One block per batch b. 512 threads = 8 waves; wave w owns H cols
// [w*64, w*64+64) for GEMM1 and D cols [w*16, w*16+16) for GEMM2.
__global__ __launch_bounds__(512, 4)
void interact_kernel(const float* __restrict__ x,   // [B, A, D] fp32
                     const float* __restrict__ W1,  // [H, D]
                     const float* __restrict__ b1,  // [H]
                     const float* __restrict__ W2,  // [D, H]
                     const float* __restrict__ b2,  // [D]
                     float* __restrict__ out)       // [B, A, D] fp32
{
    // Row strides 136/520 bf16 = 16B*odd: 16B-aligned b128, pow-2 stride broken.
    __shared__ bf16 xs[16][136];        // x_b
    __shared__ bf16 ps[2][16][136];     // pair tile, double-buffered
    __shared__ bf16 hs[16][520];        // hsum re-layout for GEMM2

    const int b    = blockIdx.x;
    const int tid  = threadIdx.x;
    const int wave = tid >> 6;
    const int lane = tid & 63;
    const int quad = lane >> 4;   // 0..3
    const int col  = lane & 15;   // 0..15

    // build-phase coords: thread owns (jrow, dq..dq+4)
    const int jrow = tid >> 5;          // 0..15
    const int dq   = (tid & 31) * 4;    // 0..124

    // ---- stage x_b into LDS as bf16; keep own chunk for the build phase ----
    bf16x4 xjb;
    {
        f32x4 v = *(const f32x4*)(x + (size_t)b * (AA * DD) + jrow * DD + dq);
        xjb = cvt4(v);
        *(bf16x4*)(&xs[jrow][dq]) = xjb;
    }

    // ---- W1 fragments, ONE-TIME load, fp32->bf16 inline (64 VGPRs) ----
    // B-operand layout: lane holds B[k = kk*32 + quad*8 + e][n = col],
    // from row-major [N,K]; W1 is [H,D] = [n][k].
    bf16x8 w1f[4][4];
    float  b1f[4];
#pragma unroll
    for (int n = 0; n < 4; ++n) {
        int h  = wave * 64 + n * 16 + col;
        b1f[n] = b1[h];
#pragma unroll
        for (int kk = 0; kk < 4; ++kk) {
            const float* s = W1 + h * DD + kk * 32 + quad * 8;
            w1f[n][kk] = cvt8(*(const f32x4*)s, *(const f32x4*)(s + 4));
        }
    }

    f32x4 hsum[4];
#pragma unroll
    for (int n = 0; n < 4; ++n) hsum[n] = splat4(0.f);

    __syncthreads();   // xs ready

    // ---- build pair tile for i=0 into ps[0] ----
    {
        bf16x4 xi = *(bf16x4*)(&xs[0][dq]);
        bf16x4 pr;
#pragma unroll
        for (int e = 0; e < 4; ++e)
            pr[e] = (bf16)((float)xjb[e] * (float)xi[e]);
        *(bf16x4*)(&ps[0][jrow][dq]) = pr;
    }
    __syncthreads();

    // ---- i-loop: ONE barrier per i (double-buffered ps) ----
    for (int i = 0; i < 16; ++i) {
        const int cur = i & 1, nxt = cur ^ 1;

        // A-operand frags for tile i (lane holds A[m=col][k=kk*32+quad*8+e])
        bf16x8 af[4];
#pragma unroll
        for (int kk = 0; kk < 4; ++kk)
            af[kk] = *(bf16x8*)(&ps[cur][col][kk * 32 + quad * 8]);

        // build tile i+1 into the other buffer (hides under the MFMAs);
        // (i+1)&15 keeps the last iteration's build in-bounds & harmless.
        {
            const int inext = (i + 1) & 15;
            bf16x4 xi = *(bf16x4*)(&xs[inext][dq]);
            bf16x4 pr;
#pragma unroll
            for (int e = 0; e < 4; ++e)
                pr[e] = (bf16)((float)xjb[e] * (float)xi[e]);
            *(bf16x4*)(&ps[nxt][jrow][dq]) = pr;
        }

        // GEMM1 tile: M=16 (j), N=64 (wave's h), K=128; acc seeded with b1
        f32x4 acc[4];
#pragma unroll
        for (int n = 0; n < 4; ++n) acc[n] = splat4(b1f[n]);
#pragma unroll
        for (int kk = 0; kk < 4; ++kk)
#pragma unroll
            for (int n = 0; n < 4; ++n)
                acc[n] = __builtin_amdgcn_mfma_f32_16x16x32_bf16(
                    af[kk], w1f[n][kk], acc[n], 0, 0, 0);

        // relu + accumulate (C/D layout: row j = quad*4+r, col h-col = lane&15)
#pragma unroll
        for (int n = 0; n < 4; ++n)
#pragma unroll
            for (int r = 0; r < 4; ++r)
                hsum[n][r] += fmaxf(acc[n][r], 0.f);

        __syncthreads();
        // After this barrier: everyone has read ps[cur] and written ps[nxt],
        // so iteration i+1 may read ps[nxt] and overwrite ps[cur].
    }

    // ---- hsum -> LDS (bf16) for GEMM2 A-operand re-layout ----
#pragma unroll
    for (int n = 0; n < 4; ++n)
#pragma unroll
        for (int r = 0; r < 4; ++r)
            hs[quad * 4 + r][wave * 64 + n * 16 + col] = (bf16)hsum[n][r];

    __syncthreads();

    // ---- GEMM2: out[j,d] = hsum[j,:] @ W2^T + 16*b2 ----
    // M=16 (j), N=16 per wave (d), K=512 (h). W2 is [D,H] row-major.
    const int d = wave * 16 + col;
    f32x4 acc2 = splat4(16.f * b2[d]);
#pragma unroll
    for (int ks = 0; ks < 16; ++ks) {
        int h0 = ks * 32 + quad * 8;
        bf16x8 a2 = *(bf16x8*)(&hs[col][h0]);
        const float* s = W2 + d * HH + h0;
        bf16x8 bw = cvt8(*(const f32x4*)s, *(const f32x4*)(s + 4));
        acc2 = __builtin_amdgcn_mfma_f32_16x16x32_bf16(a2, bw, acc2, 0, 0, 0);
    }

#pragma unroll
    for (int r = 0; r < 4; ++r)
        out[(size_t)b * (AA * DD) + (quad * 4 + r) * DD + d] = acc2[r];
}

extern "C" void kernel_launch(void* const* d_in, const int* in_sizes, int n_in,
                              void* d_out, int out_size, void* d_ws, size_t ws_size,
                              hipStream_t stream)
{
    const float* x  = (const float*)d_in[0];  // [2048,16,128]
    const float* W1 = (const float*)d_in[1];  // [512,128]
    const float* b1 = (const float*)d_in[2];  // [512]
    const float* W2 = (const float*)d_in[3];  // [128,512]
    const float* b2 = (const float*)d_in[4];  // [128]
    float* out = (float*)d_out;

    interact_kernel<<<BATCH, 512, 0, stream>>>(x, W1, b1, W2, b2, out);
}

// Round 5
// 201.842 us; speedup vs baseline: 2.4361x; 2.4361x over previous
//
#include <hip/hip_runtime.h>

// InternalInteraction: out[b,j,d] = sum_i [ relu((x_i*x_j)@W1^T + b1) @ W2^T + b2 ]
// Factored: hsum[b,j,h] = sum_i relu((x_i*x_j)@W1^T + b1); out = hsum@W2^T + 16*b2.
// B=2048, A=16, D=128, H=512. Storage fp32 (bf16-rounded values); MFMA in bf16.
//
// Round-5 structure (fixes round-4's scratch-spill catastrophe):
//  - amdgpu_waves_per_eu(2,2) pins EXACTLY 2 waves/SIMD -> 256-VGPR budget;
//    round 4's launch_bounds(512,4) capped at 128 and spilled 1.5 GB to
//    scratch; round 3's loose bounds made the compiler chase 4 waves/SIMD
//    and rematerialize W1 loads every i (L2-bound).
//  - full 16x16x128 pair tensor built once in LDS (70 KB, 1 block/CU) ->
//    the 16-iteration MFMA loop has NO barriers at all.
//  - W1 frags (64 VGPRs) loaded once; W2 frags (64 VGPRs) prefetched inside
//    the i-loop so their 256 KB/block L2 stream hides under the MFMAs and
//    GEMM2 is pure MFMA.

#define BATCH 2048
#define AA 16
#define DD 128
#define HH 512

typedef __bf16 bf16;
typedef bf16  bf16x4 __attribute__((ext_vector_type(4)));
typedef bf16  bf16x8 __attribute__((ext_vector_type(8)));
typedef float f32x4  __attribute__((ext_vector_type(4)));

__device__ inline f32x4 splat4(float v) { f32x4 r = {v, v, v, v}; return r; }

__device__ inline bf16x4 cvt4(const f32x4& v) {
    bf16x4 r;
    r[0] = (bf16)v[0]; r[1] = (bf16)v[1]; r[2] = (bf16)v[2]; r[3] = (bf16)v[3];
    return r;
}
__device__ inline bf16x8 cvt8(const f32x4& lo, const f32x4& hi) {
    bf16x8 r;
    r[0] = (bf16)lo[0]; r[1] = (bf16)lo[1]; r[2] = (bf16)lo[2]; r[3] = (bf16)lo[3];
    r[4] = (bf16)hi[0]; r[5] = (bf16)hi[1]; r[6] = (bf16)hi[2]; r[7] = (bf16)hi[3];
    return r;
}

// One block per batch b. 512 threads = 8 waves; wave w owns H cols
// [w*64, w*64+64) for GEMM1 and D cols [w*16, w*16+16) for GEMM2.
__global__ __launch_bounds__(512)
__attribute__((amdgpu_waves_per_eu(2, 2)))
void interact_kernel(const float* __restrict__ x,   // [B, A, D] fp32
                     const float* __restrict__ W1,  // [H, D]
                     const float* __restrict__ b1,  // [H]
                     const float* __restrict__ W2,  // [D, H]
                     const float* __restrict__ b2,  // [D]
                     float* __restrict__ out)       // [B, A, D] fp32
{
    // Row strides 136/520 bf16 = 16B*odd: 16B-aligned b128 reads, pow-2
    // bank stride broken (2-way aliasing is free per m136).
    __shared__ bf16 xs[16][136];          // x_b                     (4.3 KB)
    __shared__ bf16 ps[16][16][136];      // full pair tensor        (69.6 KB)
    __shared__ bf16 hs[16][520];          // hsum re-layout for GEMM2(16.6 KB)

    const int b    = blockIdx.x;
    const int tid  = threadIdx.x;
    const int wave = tid >> 6;
    const int lane = tid & 63;
    const int quad = lane >> 4;   // 0..3
    const int col  = lane & 15;   // 0..15

    // build-phase coords: thread owns (jrow, dq..dq+4)
    const int jrow = tid >> 5;          // 0..15
    const int dq   = (tid & 31) * 4;    // 0..124

    // ---- stage x_b into LDS as bf16; keep own chunk for the build phase ----
    bf16x4 xjb;
    {
        f32x4 v = *(const f32x4*)(x + (size_t)b * (AA * DD) + jrow * DD + dq);
        xjb = cvt4(v);
        *(bf16x4*)(&xs[jrow][dq]) = xjb;
    }

    // ---- W1 fragments, ONE-TIME load, fp32->bf16 inline (64 VGPRs) ----
    // B-operand layout: lane holds B[k = kk*32 + quad*8 + e][n = col],
    // from row-major [N,K]; W1 is [H,D] = [n][k].
    bf16x8 w1f[4][4];
    float  b1f[4];
#pragma unroll
    for (int n = 0; n < 4; ++n) {
        int h  = wave * 64 + n * 16 + col;
        b1f[n] = b1[h];
#pragma unroll
        for (int kk = 0; kk < 4; ++kk) {
            const float* s = W1 + h * DD + kk * 32 + quad * 8;
            w1f[n][kk] = cvt8(*(const f32x4*)s, *(const f32x4*)(s + 4));
        }
    }

    f32x4 hsum[4];
#pragma unroll
    for (int n = 0; n < 4; ++n) hsum[n] = splat4(0.f);

    __syncthreads();   // xs ready

    // ---- build ALL 16 pair tiles: ps[i][j][d] = bf16(x_i[d]*x_j[d]) ----
#pragma unroll
    for (int i = 0; i < 16; ++i) {
        bf16x4 xi = *(bf16x4*)(&xs[i][dq]);
        bf16x4 pr;
#pragma unroll
        for (int e = 0; e < 4; ++e)
            pr[e] = (bf16)((float)xjb[e] * (float)xi[e]);
        *(bf16x4*)(&ps[i][jrow][dq]) = pr;
    }
    __syncthreads();   // last barrier before the epilogue

    // ---- i-loop: BARRIER-FREE. 16 MFMAs + relu-accum per i; W2 frag for
    //      GEMM2 column set prefetched one per iteration (hides L2 stream).
    const int d2 = wave * 16 + col;       // this lane's GEMM2 output column
    bf16x8 w2f[16];                        // 64 VGPRs

    for (int i = 0; i < 16; ++i) {
        // prefetch W2 frag for ks=i: lane holds W2[d2][i*32+quad*8 .. +8]
        {
            const float* s = W2 + d2 * HH + i * 32 + quad * 8;
            w2f[i] = cvt8(*(const f32x4*)s, *(const f32x4*)(s + 4));
        }

        // A-operand frags (lane holds A[m=col][k=kk*32+quad*8+e])
        bf16x8 af[4];
#pragma unroll
        for (int kk = 0; kk < 4; ++kk)
            af[kk] = *(bf16x8*)(&ps[i][col][kk * 32 + quad * 8]);

        // GEMM1 tile: M=16 (j), N=64 (wave's h), K=128; acc seeded with b1
        f32x4 acc[4];
#pragma unroll
        for (int n = 0; n < 4; ++n) acc[n] = splat4(b1f[n]);
#pragma unroll
        for (int kk = 0; kk < 4; ++kk)
#pragma unroll
            for (int n = 0; n < 4; ++n)
                acc[n] = __builtin_amdgcn_mfma_f32_16x16x32_bf16(
                    af[kk], w1f[n][kk], acc[n], 0, 0, 0);

        // relu + accumulate (C/D layout: row j = quad*4+r, col h = lane&15)
#pragma unroll
        for (int n = 0; n < 4; ++n)
#pragma unroll
            for (int r = 0; r < 4; ++r)
                hsum[n][r] += fmaxf(acc[n][r], 0.f);
    }

    // ---- hsum -> LDS (bf16) for GEMM2 A-operand re-layout ----
#pragma unroll
    for (int n = 0; n < 4; ++n)
#pragma unroll
        for (int r = 0; r < 4; ++r)
            hs[quad * 4 + r][wave * 64 + n * 16 + col] = (bf16)hsum[n][r];

    __syncthreads();

    // ---- GEMM2: out[j,d] = hsum[j,:] @ W2^T + 16*b2 ----
    // M=16 (j), N=16 per wave (d), K=512 (h); W2 frags already in regs.
    f32x4 acc2 = splat4(16.f * b2[d2]);
#pragma unroll
    for (int ks = 0; ks < 16; ++ks) {
        bf16x8 a2 = *(bf16x8*)(&hs[col][ks * 32 + quad * 8]);
        acc2 = __builtin_amdgcn_mfma_f32_16x16x32_bf16(a2, w2f[ks], acc2, 0, 0, 0);
    }

#pragma unroll
    for (int r = 0; r < 4; ++r)
        out[(size_t)b * (AA * DD) + (quad * 4 + r) * DD + d2] = acc2[r];
}

extern "C" void kernel_launch(void* const* d_in, const int* in_sizes, int n_in,
                              void* d_out, int out_size, void* d_ws, size_t ws_size,
                              hipStream_t stream)
{
    const float* x  = (const float*)d_in[0];  // [2048,16,128]
    const float* W1 = (const float*)d_in[1];  // [512,128]
    const float* b1 = (const float*)d_in[2];  // [512]
    const float* W2 = (const float*)d_in[3];  // [128,512]
    const float* b2 = (const float*)d_in[4];  // [128]
    float* out = (float*)d_out;

    interact_kernel<<<BATCH, 512, 0, stream>>>(x, W1, b1, W2, b2, out);
}